// Round 1
// baseline (417.311 us; speedup 1.0000x reference)
//
#include <hip/hip_runtime.h>

// Problem: B=8, N=1024, DIM=1024, H=16, D=64, SCALE = 1/32.
// Inputs (fp32): x[8,1024,1024], mask[8,1023](int), pos[8,1024,1024],
//                W_qk[2048,1024], W_v[1024,1024], W_out[1024,1024], b_out[1024]
// Output fp32 [8,1024,1024].
// Workspace layout (bytes), total 75,497,472:
//   0        : xbf  [8192,1024] bf16 (16 MB)  -- reused as Obf after gemm_qkv
//   16777216 : wqkv [3072,1024] bf16 (6 MB)   (rows 0-2047 = W_qk, 2048-3071 = W_v)
//   23068672 : wout [1024,1024] bf16 (2 MB)
//   25165824 : Q    [8,16,1024,64] bf16 (16 MB)
//   41943040 : K    [8,16,1024,64] bf16 (16 MB)
//   58720256 : Vt   [8,16,64,1024] bf16 (16 MB)  (V transposed per head)

typedef unsigned short u16;
typedef short bf16x8 __attribute__((ext_vector_type(8)));
typedef float f32x4 __attribute__((ext_vector_type(4)));

#define MFMA16(a, b, c) __builtin_amdgcn_mfma_f32_16x16x32_bf16((a), (b), (c), 0, 0, 0)

__device__ __forceinline__ u16 f2bf(float f) {
    union { float f; unsigned u; } x; x.f = f;
    unsigned r = x.u + 0x7fffu + ((x.u >> 16) & 1u);
    return (u16)(r >> 16);
}

__global__ __launch_bounds__(256) void cast_f32_bf16(const float* __restrict__ src,
                                                     u16* __restrict__ dst, int n4) {
    int i = blockIdx.x * 256 + threadIdx.x;
    if (i < n4) {
        float4 v = ((const float4*)src)[i];
        ushort4 o;
        o.x = f2bf(v.x); o.y = f2bf(v.y); o.z = f2bf(v.z); o.w = f2bf(v.w);
        ((ushort4*)dst)[i] = o;
    }
}

// ---------------- QKV projection: C[8192,3072] = x_bf16 . wqkv^T ----------------
// 128x128 tile, BK=64, 4 waves each 64x64. Epilogue scatters q/k/v.
__global__ __launch_bounds__(256) void gemm_qkv(
    const u16* __restrict__ A,    // [8192][1024]
    const u16* __restrict__ Bw,   // [3072][1024]
    const float* __restrict__ pos,// [8192][1024] fp32
    u16* __restrict__ Q, u16* __restrict__ Kx, u16* __restrict__ Vt) {
    const int n0 = blockIdx.x * 128, m0 = blockIdx.y * 128;
    const int t = threadIdx.x, w = t >> 6, ln = t & 63;
    const int l15 = ln & 15, l4 = ln >> 4;
    const int wm = (w >> 1) * 64, wn = (w & 1) * 64;

    __shared__ u16 As[128][72];
    __shared__ u16 Bs[128][72];

    f32x4 acc[4][4];
#pragma unroll
    for (int i = 0; i < 4; ++i)
#pragma unroll
        for (int j = 0; j < 4; ++j) acc[i][j] = (f32x4){0.f, 0.f, 0.f, 0.f};

    const int tr = t >> 3, tc = (t & 7) * 8;
    for (int k0 = 0; k0 < 1024; k0 += 64) {
        __syncthreads();
#pragma unroll
        for (int p = 0; p < 4; ++p) {
            int row = p * 32 + tr;
            *(uint4*)&As[row][tc] = *(const uint4*)(A + (size_t)(m0 + row) * 1024 + k0 + tc);
            *(uint4*)&Bs[row][tc] = *(const uint4*)(Bw + (size_t)(n0 + row) * 1024 + k0 + tc);
        }
        __syncthreads();
#pragma unroll
        for (int kt = 0; kt < 2; ++kt) {
            bf16x8 a[4], bfr[4];
#pragma unroll
            for (int mt = 0; mt < 4; ++mt)
                a[mt] = *(const bf16x8*)&As[wm + mt * 16 + l15][kt * 32 + l4 * 8];
#pragma unroll
            for (int nt = 0; nt < 4; ++nt)
                bfr[nt] = *(const bf16x8*)&Bs[wn + nt * 16 + l15][kt * 32 + l4 * 8];
#pragma unroll
            for (int mt = 0; mt < 4; ++mt)
#pragma unroll
                for (int nt = 0; nt < 4; ++nt)
                    acc[mt][nt] = MFMA16(a[mt], bfr[nt], acc[mt][nt]);
        }
    }
    // epilogue: C-layout col = lane&15, row = (lane>>4)*4 + r
#pragma unroll
    for (int mt = 0; mt < 4; ++mt)
#pragma unroll
        for (int nt = 0; nt < 4; ++nt)
#pragma unroll
            for (int r = 0; r < 4; ++r) {
                int i = m0 + wm + mt * 16 + l4 * 4 + r;   // 0..8191 = b*1024+n
                int j = n0 + wn + nt * 16 + l15;          // 0..3071
                float v = acc[mt][nt][r];
                int bb = i >> 10, n = i & 1023;
                if (j < 2048) {
                    int jj = j & 1023;
                    v += pos[(size_t)i * 1024 + jj];
                    u16 bf = f2bf(v);
                    int hh = jj >> 6, dd = jj & 63;
                    size_t idx = (((size_t)(bb * 16 + hh)) * 1024 + n) * 64 + dd;
                    if (j < 1024) Q[idx] = bf; else Kx[idx] = bf;
                } else {
                    int jj = j - 2048;
                    int hh = jj >> 6, dd = jj & 63;
                    Vt[(((size_t)(bb * 16 + hh)) * 64 + dd) * 1024 + n] = f2bf(v);
                }
            }
}

// ---------------- Flash attention: one block per (b,h,q-tile of 128) ----------------
__global__ __launch_bounds__(256) void attn_kernel(
    const u16* __restrict__ Q,    // [B*H][1024][64]
    const u16* __restrict__ Kx,   // [B*H][1024][64]
    const u16* __restrict__ Vt,   // [B*H][64][1024]
    const int* __restrict__ maskIn, // [B][1023]
    u16* __restrict__ O) {        // [B][1024][1024]  (b,n,h*64+d)
    const int qt = blockIdx.x;    // 0..7
    const int bh = blockIdx.y;    // 0..127
    const int b = bh >> 4, h = bh & 15;
    const int t = threadIdx.x, w = t >> 6, ln = t & 63;
    const int l15 = ln & 15, l4 = ln >> 4;

    __shared__ u16 Ks[128][72];
    __shared__ u16 Vs[64][136];
    __shared__ u16 Ps[4][32][136];
    __shared__ unsigned char mch[1024];

    for (int i = t; i < 1024; i += 256)
        mch[i] = (i == 0) ? (unsigned char)1 : (unsigned char)(maskIn[b * 1023 + i - 1] != 0);
    __syncthreads();

    const size_t qkbase = (size_t)bh * 65536;  // 1024*64
    const int q0 = qt * 128 + w * 32;

    // Q fragments (A layout): rows q0+mt*16+l15, k = kt*32 + l4*8
    bf16x8 aq[2][2];
#pragma unroll
    for (int mt = 0; mt < 2; ++mt)
#pragma unroll
        for (int kt = 0; kt < 2; ++kt)
            aq[mt][kt] = *(const bf16x8*)(Q + qkbase + (size_t)(q0 + mt * 16 + l15) * 64 + kt * 32 + l4 * 8);

    bool rq[2][4];
    float mrow[2][4], lrow[2][4];
    f32x4 o[2][4];
#pragma unroll
    for (int mt = 0; mt < 2; ++mt)
#pragma unroll
        for (int r = 0; r < 4; ++r) {
            rq[mt][r] = mch[q0 + mt * 16 + l4 * 4 + r] != 0;
            mrow[mt][r] = -1e30f;
            lrow[mt][r] = 0.f;
        }
#pragma unroll
    for (int mt = 0; mt < 2; ++mt)
#pragma unroll
        for (int nt = 0; nt < 4; ++nt) o[mt][nt] = (f32x4){0.f, 0.f, 0.f, 0.f};

    for (int j0 = 0; j0 < 1024; j0 += 128) {
        __syncthreads();
        {
            int tr = t >> 3, tc = (t & 7) * 8;
#pragma unroll
            for (int p = 0; p < 4; ++p) {
                int row = p * 32 + tr;
                *(uint4*)&Ks[row][tc] = *(const uint4*)(Kx + qkbase + (size_t)(j0 + row) * 64 + tc);
            }
            int vr = t >> 4, vc = (t & 15) * 8;
#pragma unroll
            for (int p = 0; p < 4; ++p) {
                int row = p * 16 + vr;
                *(uint4*)&Vs[row][vc] = *(const uint4*)(Vt + (size_t)bh * 65536 + (size_t)row * 1024 + j0 + vc);
            }
        }
        __syncthreads();

        // S = Q K^T
        f32x4 s[2][8];
#pragma unroll
        for (int mt = 0; mt < 2; ++mt)
#pragma unroll
            for (int nt = 0; nt < 8; ++nt) s[mt][nt] = (f32x4){0.f, 0.f, 0.f, 0.f};
#pragma unroll
        for (int nt = 0; nt < 8; ++nt) {
            bf16x8 bk0 = *(const bf16x8*)&Ks[nt * 16 + l15][l4 * 8];
            bf16x8 bk1 = *(const bf16x8*)&Ks[nt * 16 + l15][32 + l4 * 8];
#pragma unroll
            for (int mt = 0; mt < 2; ++mt) {
                s[mt][nt] = MFMA16(aq[mt][0], bk0, s[mt][nt]);
                s[mt][nt] = MFMA16(aq[mt][1], bk1, s[mt][nt]);
            }
        }
        // scale + mask + rowmax
        float mx[2][4];
#pragma unroll
        for (int mt = 0; mt < 2; ++mt)
#pragma unroll
            for (int r = 0; r < 4; ++r) mx[mt][r] = -1e30f;
#pragma unroll
        for (int nt = 0; nt < 8; ++nt) {
            bool cv = mch[j0 + nt * 16 + l15] != 0;
#pragma unroll
            for (int mt = 0; mt < 2; ++mt)
#pragma unroll
                for (int r = 0; r < 4; ++r) {
                    float v = s[mt][nt][r] * 0.03125f;
                    v = (rq[mt][r] && cv) ? v : -1e30f;
                    s[mt][nt][r] = v;
                    mx[mt][r] = fmaxf(mx[mt][r], v);
                }
        }
#pragma unroll
        for (int d = 1; d < 16; d <<= 1)
#pragma unroll
            for (int mt = 0; mt < 2; ++mt)
#pragma unroll
                for (int r = 0; r < 4; ++r)
                    mx[mt][r] = fmaxf(mx[mt][r], __shfl_xor(mx[mt][r], d));

        float alpha[2][4], rs[2][4];
#pragma unroll
        for (int mt = 0; mt < 2; ++mt)
#pragma unroll
            for (int r = 0; r < 4; ++r) {
                float mn = fmaxf(mrow[mt][r], mx[mt][r]);
                alpha[mt][r] = __expf(mrow[mt][r] - mn);
                mrow[mt][r] = mn;
                rs[mt][r] = 0.f;
            }
        // p = exp(s - m); write P to per-wave LDS in row-major [32][128]
#pragma unroll
        for (int nt = 0; nt < 8; ++nt)
#pragma unroll
            for (int mt = 0; mt < 2; ++mt)
#pragma unroll
                for (int r = 0; r < 4; ++r) {
                    float p = __expf(s[mt][nt][r] - mrow[mt][r]);
                    rs[mt][r] += p;
                    Ps[w][mt * 16 + l4 * 4 + r][nt * 16 + l15] = f2bf(p);
                }
#pragma unroll
        for (int d = 1; d < 16; d <<= 1)
#pragma unroll
            for (int mt = 0; mt < 2; ++mt)
#pragma unroll
                for (int r = 0; r < 4; ++r)
                    rs[mt][r] += __shfl_xor(rs[mt][r], d);
#pragma unroll
        for (int mt = 0; mt < 2; ++mt)
#pragma unroll
            for (int r = 0; r < 4; ++r)
                lrow[mt][r] = alpha[mt][r] * lrow[mt][r] + rs[mt][r];
        // rescale O
#pragma unroll
        for (int mt = 0; mt < 2; ++mt)
#pragma unroll
            for (int nt = 0; nt < 4; ++nt)
#pragma unroll
                for (int r = 0; r < 4; ++r)
                    o[mt][nt][r] *= alpha[mt][r];
        // O += P.V   (A = P from LDS, B = Vt rows = d)
#pragma unroll
        for (int kt = 0; kt < 4; ++kt) {
            bf16x8 ap0 = *(const bf16x8*)&Ps[w][l15][kt * 32 + l4 * 8];
            bf16x8 ap1 = *(const bf16x8*)&Ps[w][16 + l15][kt * 32 + l4 * 8];
#pragma unroll
            for (int nt = 0; nt < 4; ++nt) {
                bf16x8 bv = *(const bf16x8*)&Vs[nt * 16 + l15][kt * 32 + l4 * 8];
                o[0][nt] = MFMA16(ap0, bv, o[0][nt]);
                o[1][nt] = MFMA16(ap1, bv, o[1][nt]);
            }
        }
    }
    // epilogue: O[b][n][h*64+d]
#pragma unroll
    for (int mt = 0; mt < 2; ++mt)
#pragma unroll
        for (int nt = 0; nt < 4; ++nt)
#pragma unroll
            for (int r = 0; r < 4; ++r) {
                int n = q0 + mt * 16 + l4 * 4 + r;
                int d = nt * 16 + l15;
                float val = o[mt][nt][r] / lrow[mt][r];
                O[((size_t)(b * 1024 + n)) * 1024 + h * 64 + d] = f2bf(val);
            }
}

// ---------------- Output projection: out[8192,1024] = Obf . wout^T + b ----------------
__global__ __launch_bounds__(256) void gemm_out(
    const u16* __restrict__ A,    // [8192][1024]
    const u16* __restrict__ Bw,   // [1024][1024]
    const float* __restrict__ bias,
    float* __restrict__ out) {
    const int n0 = blockIdx.x * 128, m0 = blockIdx.y * 128;
    const int t = threadIdx.x, w = t >> 6, ln = t & 63;
    const int l15 = ln & 15, l4 = ln >> 4;
    const int wm = (w >> 1) * 64, wn = (w & 1) * 64;

    __shared__ u16 As[128][72];
    __shared__ u16 Bs[128][72];

    f32x4 acc[4][4];
#pragma unroll
    for (int i = 0; i < 4; ++i)
#pragma unroll
        for (int j = 0; j < 4; ++j) acc[i][j] = (f32x4){0.f, 0.f, 0.f, 0.f};

    const int tr = t >> 3, tc = (t & 7) * 8;
    for (int k0 = 0; k0 < 1024; k0 += 64) {
        __syncthreads();
#pragma unroll
        for (int p = 0; p < 4; ++p) {
            int row = p * 32 + tr;
            *(uint4*)&As[row][tc] = *(const uint4*)(A + (size_t)(m0 + row) * 1024 + k0 + tc);
            *(uint4*)&Bs[row][tc] = *(const uint4*)(Bw + (size_t)(n0 + row) * 1024 + k0 + tc);
        }
        __syncthreads();
#pragma unroll
        for (int kt = 0; kt < 2; ++kt) {
            bf16x8 a[4], bfr[4];
#pragma unroll
            for (int mt = 0; mt < 4; ++mt)
                a[mt] = *(const bf16x8*)&As[wm + mt * 16 + l15][kt * 32 + l4 * 8];
#pragma unroll
            for (int nt = 0; nt < 4; ++nt)
                bfr[nt] = *(const bf16x8*)&Bs[wn + nt * 16 + l15][kt * 32 + l4 * 8];
#pragma unroll
            for (int mt = 0; mt < 4; ++mt)
#pragma unroll
                for (int nt = 0; nt < 4; ++nt)
                    acc[mt][nt] = MFMA16(a[mt], bfr[nt], acc[mt][nt]);
        }
    }
#pragma unroll
    for (int mt = 0; mt < 4; ++mt)
#pragma unroll
        for (int nt = 0; nt < 4; ++nt)
#pragma unroll
            for (int r = 0; r < 4; ++r) {
                int i = m0 + wm + mt * 16 + l4 * 4 + r;
                int j = n0 + wn + nt * 16 + l15;
                out[(size_t)i * 1024 + j] = acc[mt][nt][r] + bias[j];
            }
}

extern "C" void kernel_launch(void* const* d_in, const int* in_sizes, int n_in,
                              void* d_out, int out_size, void* d_ws, size_t ws_size,
                              hipStream_t stream) {
    const float* x    = (const float*)d_in[0];
    const int*   mask = (const int*)d_in[1];
    const float* pos  = (const float*)d_in[2];
    const float* wqk  = (const float*)d_in[3];
    const float* wv   = (const float*)d_in[4];
    const float* wout = (const float*)d_in[5];
    const float* bout = (const float*)d_in[6];

    char* ws = (char*)d_ws;
    u16* xbf    = (u16*)(ws + 0);           // also Obf after attention
    u16* wqkvbf = (u16*)(ws + 16777216);
    u16* woutbf = (u16*)(ws + 23068672);
    u16* Qb     = (u16*)(ws + 25165824);
    u16* Kb     = (u16*)(ws + 41943040);
    u16* Vtb    = (u16*)(ws + 58720256);

    cast_f32_bf16<<<8192, 256, 0, stream>>>(x, xbf, 2097152);
    cast_f32_bf16<<<2048, 256, 0, stream>>>(wqk, wqkvbf, 524288);
    cast_f32_bf16<<<1024, 256, 0, stream>>>(wv, wqkvbf + 2097152, 262144);
    cast_f32_bf16<<<1024, 256, 0, stream>>>(wout, woutbf, 262144);

    gemm_qkv<<<dim3(24, 64), 256, 0, stream>>>(xbf, wqkvbf, pos, Qb, Kb, Vtb);
    attn_kernel<<<dim3(8, 128), 256, 0, stream>>>(Qb, Kb, Vtb, mask, xbf);
    gemm_out<<<dim3(8, 64), 256, 0, stream>>>(xbf, woutbf, bout, (float*)d_out);
}